// Round 2
// baseline (1350.030 us; speedup 1.0000x reference)
//
#include <hip/hip_runtime.h>
#include <hip/hip_fp16.h>
#include <cstdint>

using f16 = _Float16;
typedef __attribute__((ext_vector_type(8))) _Float16 f16x8;
typedef __attribute__((ext_vector_type(4))) float f32x4;

#define MFMA16(a, b, c) __builtin_amdgcn_mfma_f32_16x16x32_f16((a), (b), (c), 0, 0, 0)

__device__ __forceinline__ f16x8 ldfrag(const f16* p) { return *(const f16x8*)p; }

// Problem constants: B=8, T=1024, K=128, H=8 -> M = B*H = 64 scrambled batches.
static const int64_t NX = 1048576;   // x elements: 8*1024*128
static const int64_t NW = 655360;    // Wq/Wk elements: 1024*128*5
static const int64_t NV = 131072;    // Wv / Wu elements: 1024*128

// ---------------- K0: split-convert/repack weights and x to fp16 hi/lo -----
__global__ __launch_bounds__(256) void k0_prep(
    const float* __restrict__ x, const float* __restrict__ Wq,
    const float* __restrict__ Wk, const float* __restrict__ Wv,
    const float* __restrict__ Wu,
    f16* __restrict__ xh, f16* __restrict__ xl,
    f16* __restrict__ Wqh, f16* __restrict__ Wql,
    f16* __restrict__ Wkh, f16* __restrict__ Wkl,
    f16* __restrict__ Wvb, f16* __restrict__ Wub) {
  int64_t i = (int64_t)blockIdx.x * 256 + threadIdx.x;  // grid sized exactly
  if (i < NX) {
    const float v = x[i];
    const f16 h = (f16)v;
    xh[i] = h; xl[i] = (f16)(v - (float)h);
  } else if (i < NX + NW) {
    int64_t d = i - NX;
    int j = (int)(d >> 17);
    int rem = (int)(d & 131071);
    int o = rem >> 7, c = rem & 127;
    const float v = Wq[(int64_t)(o * 128 + c) * 5 + j];   // layout [j][o][c]
    const f16 h = (f16)v;
    Wqh[d] = h; Wql[d] = (f16)(v - (float)h);
  } else if (i < NX + 2 * NW) {
    int64_t d = i - NX - NW;
    int j = (int)(d >> 17);
    int rem = (int)(d & 131071);
    int o = rem >> 7, c = rem & 127;
    const float v = Wk[(int64_t)(o * 128 + c) * 5 + j];
    const f16 h = (f16)v;
    Wkh[d] = h; Wkl[d] = (f16)(v - (float)h);
  } else if (i < NX + 2 * NW + NV) {
    int64_t d = i - NX - 2 * NW;
    Wvb[d] = (f16)Wv[d];                                // [o][c]
  } else {
    int64_t d = i - NX - 2 * NW - NV;
    Wub[d] = (f16)Wu[d];                                // [c][o]
  }
}

// ---------------- K1: causal convs (split-f16, 5 shifted GEMMs) ------------
// q3/k3: [m=64][t2=1024][kc=128] hi+lo fp16 (scaled); v3T: [m][kc][t2] fp16.
__global__ __launch_bounds__(256) void k1_conv(
    const f16* __restrict__ xh, const f16* __restrict__ xl,
    const f16* __restrict__ Wqh, const f16* __restrict__ Wql,
    const f16* __restrict__ Wkh, const f16* __restrict__ Wkl,
    const f16* __restrict__ Wvb,
    const float* __restrict__ bq, const float* __restrict__ bk,
    const float* __restrict__ bv,
    f16* __restrict__ q3h, f16* __restrict__ q3l,
    f16* __restrict__ k3h, f16* __restrict__ k3l,
    f16* __restrict__ v3T) {
  const int w = threadIdx.x >> 6, lane = threadIdx.x & 63;
  const int quad = lane >> 4, lo = lane & 15;
  const int r0 = blockIdx.x * 64 + w * 16;   // global row = b*1024 + t
  const int bb = r0 >> 10;                   // batch (same for all 16 rows)
  const int o0 = blockIdx.y * 128;           // output-channel block

  f32x4 aq[8], ak[8], av[8];
#pragma unroll
  for (int i = 0; i < 8; ++i) {
#pragma unroll
    for (int r = 0; r < 4; ++r) { aq[i][r] = 0.f; ak[i][r] = 0.f; av[i][r] = 0.f; }
  }

  const int t = (r0 + lo) & 1023;  // per-lane time index
#pragma unroll
  for (int j = 0; j < 5; ++j) {
    const int tp = t + j - 4;                 // causal left-pad 4
    const bool ok = (tp >= 0);
    const int tpc = ok ? tp : 0;
    const int64_t xoff = ((int64_t)(bb * 1024 + tpc)) * 128;
#pragma unroll
    for (int kk = 0; kk < 4; ++kk) {
      const int koff = kk * 32 + quad * 8;
      f16x8 ah = ldfrag(xh + xoff + koff);
      f16x8 al = ldfrag(xl + xoff + koff);
      if (!ok) {
#pragma unroll
        for (int e = 0; e < 8; ++e) { ah[e] = (f16)0; al[e] = (f16)0; }
      }
#pragma unroll
      for (int nt = 0; nt < 8; ++nt) {
        const int n = o0 + nt * 16 + lo;
        const int64_t wi = (int64_t)j * 131072 + (int64_t)n * 128 + koff;
        f16x8 bh = ldfrag(Wqh + wi);
        f16x8 bl = ldfrag(Wql + wi);
        aq[nt] = MFMA16(ah, bh, aq[nt]);   // hi*hi
        aq[nt] = MFMA16(ah, bl, aq[nt]);   // hi*lo
        aq[nt] = MFMA16(al, bh, aq[nt]);   // lo*hi
        bh = ldfrag(Wkh + wi);
        bl = ldfrag(Wkl + wi);
        ak[nt] = MFMA16(ah, bh, ak[nt]);
        ak[nt] = MFMA16(ah, bl, ak[nt]);
        ak[nt] = MFMA16(al, bh, ak[nt]);
        if (j == 4) {  // pointwise V conv uses x[t] (tap aligned with j==4)
          f16x8 bv8 = ldfrag(Wvb + (int64_t)n * 128 + koff);
          av[nt] = MFMA16(ah, bv8, av[nt]);
        }
      }
    }
  }

  const float SC = 0.29730177875068026f;  // 128^-0.25
#pragma unroll
  for (int nt = 0; nt < 8; ++nt) {
    const int o = o0 + nt * 16 + lo;
    const float vbq = bq[o], vbk = bk[o], vbv = bv[o];
    const int kc = o >> 3, hh = o & 7;
#pragma unroll
    for (int r = 0; r < 4; ++r) {
      const int row = r0 + quad * 4 + r;       // b*1024 + t
      const int m = row >> 7;                  // b*8 + (t>>7)
      const int t2 = (row & 127) * 8 + hh;     // (t&127)*8 + h
      const int64_t idx = ((int64_t)m * 1024 + t2) * 128 + kc;
      const float qf = (aq[nt][r] + vbq) * SC;
      const f16 qhi = (f16)qf;
      q3h[idx] = qhi; q3l[idx] = (f16)(qf - (float)qhi);
      const float kf = (ak[nt][r] + vbk) * SC;
      const f16 khi = (f16)kf;
      k3h[idx] = khi; k3l[idx] = (f16)(kf - (float)khi);
      v3T[((int64_t)m * 128 + kc) * 1024 + t2] = (f16)(av[nt][r] + vbv);
    }
  }
}

// ---------------- K2: scores S = Q3 @ K3^T (split-f16), fp32 out -----------
__global__ __launch_bounds__(256) void k2_scores(
    const f16* __restrict__ q3h, const f16* __restrict__ q3l,
    const f16* __restrict__ k3h, const f16* __restrict__ k3l,
    float* __restrict__ SP, int m_base) {
  const int w = threadIdx.x >> 6, lane = threadIdx.x & 63;
  const int quad = lane >> 4, lo = lane & 15;
  const int mm = blockIdx.z;
  const int m = m_base + mm;
  const int r0 = blockIdx.x * 64 + w * 16;  // t2 rows
  const int s0 = blockIdx.y * 128;          // s cols

  f32x4 acc[8];
#pragma unroll
  for (int i = 0; i < 8; ++i)
#pragma unroll
    for (int r = 0; r < 4; ++r) acc[i][r] = 0.f;

  const int64_t qoff = ((int64_t)m * 1024 + r0 + lo) * 128;
  const int64_t koffb = ((int64_t)m * 1024 + s0 + lo) * 128;
#pragma unroll
  for (int kk = 0; kk < 4; ++kk) {
    const int koff = kk * 32 + quad * 8;
    f16x8 ah = ldfrag(q3h + qoff + koff);
    f16x8 al = ldfrag(q3l + qoff + koff);
#pragma unroll
    for (int nt = 0; nt < 8; ++nt) {
      const int64_t bi = koffb + (int64_t)nt * 16 * 128 + koff;
      f16x8 bh = ldfrag(k3h + bi);
      f16x8 bl = ldfrag(k3l + bi);
      acc[nt] = MFMA16(ah, bh, acc[nt]);
      acc[nt] = MFMA16(ah, bl, acc[nt]);
      acc[nt] = MFMA16(al, bh, acc[nt]);
    }
  }
#pragma unroll
  for (int nt = 0; nt < 8; ++nt)
#pragma unroll
    for (int r = 0; r < 4; ++r) {
      const int row = r0 + quad * 4 + r, col = s0 + nt * 16 + lo;
      SP[((int64_t)mm * 1024 + row) * 1024 + col] = acc[nt][r];
    }
}

// ---------------- K3: exact fp32 top-64 + rowmin + causal + softmax --------
__global__ __launch_bounds__(256) void k3_select(
    const float* __restrict__ SP, f16* __restrict__ P) {
  const int w = threadIdx.x >> 6, lane = threadIdx.x & 63;
  const int t2 = blockIdx.x * 4 + w;  // one wave per row
  const int mm = blockIdx.y;
  const float* row = SP + ((int64_t)mm * 1024 + t2) * 1024;

  float v[16];
  unsigned key[16];
  float mn = 1e30f;
  unsigned kmax = 0, kmin = 0xFFFFFFFFu;
#pragma unroll
  for (int i = 0; i < 16; ++i) {
    const float f = row[i * 64 + lane];
    v[i] = f;
    const unsigned u = __builtin_bit_cast(unsigned, f);
    const unsigned k = (u & 0x80000000u) ? ~u : (u | 0x80000000u);  // monotonic
    key[i] = k;
    mn = fminf(mn, f);
    kmax = max(kmax, k);
    kmin = min(kmin, k);
  }
  for (int off = 32; off; off >>= 1) {
    mn = fminf(mn, __shfl_xor(mn, off));
    kmax = max(kmax, (unsigned)__shfl_xor((int)kmax, off));
    kmin = min(kmin, (unsigned)__shfl_xor((int)kmin, off));
  }

  // largest T in [kmin, kmax] with count(key >= T) >= 64  (exact fp32 top-64)
  unsigned long long blo = kmin, bhi = kmax;
  while (blo < bhi) {
    const unsigned long long mid = blo + ((bhi - blo + 1) >> 1);
    int cnt = 0;
#pragma unroll
    for (int i = 0; i < 16; ++i) cnt += (key[i] >= (unsigned)mid) ? 1 : 0;
    for (int off = 32; off; off >>= 1) cnt += __shfl_xor(cnt, off);
    if (cnt >= 64) blo = mid; else bhi = mid - 1;
  }
  const unsigned kth = (unsigned)blo;

  float wv[16];
  float mx = -1e30f;
#pragma unroll
  for (int i = 0; i < 16; ++i) {
    const int s = i * 64 + lane;
    const float ww = (key[i] >= kth) ? v[i] : mn;
    wv[i] = ww;
    if (s <= t2) mx = fmaxf(mx, ww);
  }
  for (int off = 32; off; off >>= 1) mx = fmaxf(mx, __shfl_xor(mx, off));

  float e[16];
  float sum = 0.f;
#pragma unroll
  for (int i = 0; i < 16; ++i) {
    const int s = i * 64 + lane;
    const float ev = (s <= t2) ? expf(wv[i] - mx) : 0.f;
    e[i] = ev;
    sum += ev;
  }
  for (int off = 32; off; off >>= 1) sum += __shfl_xor(sum, off);
  const float inv = 1.0f / sum;
  f16* prow = P + ((int64_t)mm * 1024 + t2) * 1024;
#pragma unroll
  for (int i = 0; i < 16; ++i) prow[i * 64 + lane] = (f16)(e[i] * inv);
}

// ---------------- K4: A = P @ V (per m) ------------------------------------
__global__ __launch_bounds__(256) void k4_pv(
    const f16* __restrict__ P, const f16* __restrict__ v3T,
    f16* __restrict__ A, int m_base) {
  const int w = threadIdx.x >> 6, lane = threadIdx.x & 63;
  const int quad = lane >> 4, lo = lane & 15;
  const int mm = blockIdx.y;
  const int m = m_base + mm;
  const int r0 = blockIdx.x * 64 + w * 16;

  f32x4 acc[8];
#pragma unroll
  for (int i = 0; i < 8; ++i)
#pragma unroll
    for (int r = 0; r < 4; ++r) acc[i][r] = 0.f;

  const f16* prow = P + ((int64_t)mm * 1024 + r0 + lo) * 1024;
  const f16* vbase = v3T + ((int64_t)m * 128 + lo) * 1024;
  for (int ks = 0; ks < 32; ++ks) {
    const int koff = ks * 32 + quad * 8;
    f16x8 a = ldfrag(prow + koff);
#pragma unroll
    for (int nt = 0; nt < 8; ++nt) {
      f16x8 fb = ldfrag(vbase + (int64_t)nt * 16 * 1024 + koff);
      acc[nt] = MFMA16(a, fb, acc[nt]);
    }
  }
#pragma unroll
  for (int nt = 0; nt < 8; ++nt)
#pragma unroll
    for (int r = 0; r < 4; ++r) {
      const int row = r0 + quad * 4 + r, col = nt * 16 + lo;
      A[((int64_t)m * 1024 + row) * 128 + col] = (f16)acc[nt][r];
    }
}

// ---------------- K5: gather + output projection + bias --------------------
__global__ __launch_bounds__(256) void k5_proj(
    const f16* __restrict__ A, const f16* __restrict__ Wub,
    const float* __restrict__ bu, float* __restrict__ out) {
  const int w = threadIdx.x >> 6, lane = threadIdx.x & 63;
  const int quad = lane >> 4, lo = lane & 15;
  const int r0 = blockIdx.x * 64 + w * 16;  // row in [0, 8192) = b*1024 + t2
  const int r = r0 + lo;
  const int bI = r >> 10, t2 = r & 1023;

  f32x4 acc[8];
#pragma unroll
  for (int i = 0; i < 8; ++i)
#pragma unroll
    for (int rr = 0; rr < 4; ++rr) acc[i][rr] = 0.f;

  for (int kk = 0; kk < 32; ++kk) {
    const int o = kk * 32 + quad * 8;  // feature index 0..1023
    const int j = o >> 7, kc = o & 127;
    f16x8 a = ldfrag(A + (((int64_t)(bI * 8 + j) * 1024 + t2) * 128 + kc));
#pragma unroll
    for (int nt = 0; nt < 8; ++nt) {
      f16x8 fb = ldfrag(Wub + (int64_t)(nt * 16 + lo) * 1024 + o);
      acc[nt] = MFMA16(a, fb, acc[nt]);
    }
  }
#pragma unroll
  for (int nt = 0; nt < 8; ++nt) {
    const int col = nt * 16 + lo;
    const float bias = bu[col];
#pragma unroll
    for (int rr = 0; rr < 4; ++rr) {
      const int row = r0 + quad * 4 + rr;
      out[(int64_t)row * 128 + col] = acc[nt][rr] + bias;
    }
  }
}

// ---------------- launcher --------------------------------------------------
extern "C" void kernel_launch(void* const* d_in, const int* in_sizes, int n_in,
                              void* d_out, int out_size, void* d_ws, size_t ws_size,
                              hipStream_t stream) {
  const float* x  = (const float*)d_in[0];
  const float* Wq = (const float*)d_in[1];
  const float* bq = (const float*)d_in[2];
  const float* Wk = (const float*)d_in[3];
  const float* bk = (const float*)d_in[4];
  const float* Wv = (const float*)d_in[5];
  const float* bv = (const float*)d_in[6];
  const float* Wu = (const float*)d_in[7];
  const float* bu = (const float*)d_in[8];
  float* out = (float*)d_out;

  char* ws = (char*)d_ws;
  f16* xh  = (f16*)ws;  ws += 2097152;
  f16* xl  = (f16*)ws;  ws += 2097152;
  f16* Wqh = (f16*)ws;  ws += 1310720;
  f16* Wql = (f16*)ws;  ws += 1310720;
  f16* Wkh = (f16*)ws;  ws += 1310720;
  f16* Wkl = (f16*)ws;  ws += 1310720;
  f16* Wvb = (f16*)ws;  ws += 262144;
  f16* Wub = (f16*)ws;  ws += 262144;
  f16* q3h = (f16*)ws;  ws += 16777216;           // 64*1024*128 fp16
  f16* q3l = (f16*)ws;  ws += 16777216;
  f16* k3h = (f16*)ws;  ws += 16777216;
  f16* k3l = (f16*)ws;  ws += 16777216;
  f16* v3T = (f16*)ws;  ws += 16777216;
  f16* A   = (f16*)ws;  ws += 16777216;
  // fixed bytes so far: 110,624,768
  // per-chunk: SP fp32 (mch*4 MiB) + P fp16 (mch*2 MiB)
  int mch = 16;
  while (mch > 1 &&
         (size_t)110624768 + (size_t)mch * 6291456 > ws_size) mch >>= 1;
  float* SP = (float*)ws;  ws += (size_t)mch * 4194304;
  f16*   P  = (f16*)ws;

  // K0: repack (exactly 2621440 threads = 10240 * 256)
  k0_prep<<<10240, 256, 0, stream>>>(x, Wq, Wk, Wv, Wu,
                                     xh, xl, Wqh, Wql, Wkh, Wkl, Wvb, Wub);

  // K1: convs + scramble (8192 rows / 64 per block, 1024 ch / 128 per block)
  k1_conv<<<dim3(128, 8), 256, 0, stream>>>(xh, xl, Wqh, Wql, Wkh, Wkl, Wvb,
                                            bq, bk, bv, q3h, q3l, k3h, k3l, v3T);

  // attention in chunks of mch m-batches
  for (int m_base = 0; m_base < 64; m_base += mch) {
    k2_scores<<<dim3(16, 8, mch), 256, 0, stream>>>(q3h, q3l, k3h, k3l, SP, m_base);
    k3_select<<<dim3(256, mch), 256, 0, stream>>>(SP, P);
    k4_pv<<<dim3(16, mch), 256, 0, stream>>>(P, v3T, A, m_base);
  }

  // K5: projection (8192 rows / 64 per block)
  k5_proj<<<128, 256, 0, stream>>>(A, Wub, bu, out);

  (void)in_sizes; (void)n_in; (void)out_size; (void)ws_size;
}

// Round 3
// 1056.835 us; speedup vs baseline: 1.2774x; 1.2774x over previous
//
#include <hip/hip_runtime.h>
#include <hip/hip_fp16.h>
#include <cstdint>

using f16 = _Float16;
typedef __attribute__((ext_vector_type(8))) _Float16 f16x8;
typedef __attribute__((ext_vector_type(4))) _Float16 f16x4;
typedef __attribute__((ext_vector_type(4))) float f32x4;

#define MFMA16(a, b, c) __builtin_amdgcn_mfma_f32_16x16x32_f16((a), (b), (c), 0, 0, 0)

__device__ __forceinline__ f16x8 ldfrag(const f16* p) { return *(const f16x8*)p; }

// Problem constants: B=8, T=1024, K=128, H=8 -> M = B*H = 64 scrambled batches.
static const int64_t NX = 1048576;   // x elements: 8*1024*128
static const int64_t NW = 655360;    // Wq/Wk elements: 1024*128*5
static const int64_t NV = 131072;    // Wv / Wu elements: 1024*128

// ---------------- K0: split-convert/repack weights and x to fp16 hi/lo -----
__global__ __launch_bounds__(256) void k0_prep(
    const float* __restrict__ x, const float* __restrict__ Wq,
    const float* __restrict__ Wk, const float* __restrict__ Wv,
    const float* __restrict__ Wu,
    f16* __restrict__ xh, f16* __restrict__ xl,
    f16* __restrict__ Wqh, f16* __restrict__ Wql,
    f16* __restrict__ Wkh, f16* __restrict__ Wkl,
    f16* __restrict__ Wvb, f16* __restrict__ Wub) {
  int64_t i = (int64_t)blockIdx.x * 256 + threadIdx.x;  // grid sized exactly
  if (i < NX) {
    const float v = x[i];
    const f16 h = (f16)v;
    xh[i] = h; xl[i] = (f16)(v - (float)h);
  } else if (i < NX + NW) {
    int64_t d = i - NX;
    int j = (int)(d >> 17);
    int rem = (int)(d & 131071);
    int o = rem >> 7, c = rem & 127;
    const float v = Wq[(int64_t)(o * 128 + c) * 5 + j];   // layout [j][o][c]
    const f16 h = (f16)v;
    Wqh[d] = h; Wql[d] = (f16)(v - (float)h);
  } else if (i < NX + 2 * NW) {
    int64_t d = i - NX - NW;
    int j = (int)(d >> 17);
    int rem = (int)(d & 131071);
    int o = rem >> 7, c = rem & 127;
    const float v = Wk[(int64_t)(o * 128 + c) * 5 + j];
    const f16 h = (f16)v;
    Wkh[d] = h; Wkl[d] = (f16)(v - (float)h);
  } else if (i < NX + 2 * NW + NV) {
    int64_t d = i - NX - 2 * NW;
    Wvb[d] = (f16)Wv[d];                                // [o][c]
  } else {
    int64_t d = i - NX - 2 * NW - NV;
    Wub[d] = (f16)Wu[d];                                // [c][o]
  }
}

// ---------------- K1: causal convs (split-f16) + LDS-staged coalesced out --
// One block = 32 rows x all 1024 channels. The scrambled targets of this
// block form DENSE regions: q3/k3 rows t2 in [(r0&127)*8, +256), all kc;
// v3T all kc x 256 consecutive t2. Stage through LDS, store f16x8 coalesced.
// q3/k3: [m=64][t2=1024][kc=128] hi+lo fp16 (scaled); v3T: [m][kc][t2] fp16.
#define STAGE_QK(DST, VALEXPR)                                          \
  {                                                                     \
    __syncthreads();                                                    \
    _Pragma("unroll")                                                   \
    for (int nt = 0; nt < 8; ++nt) {                                    \
      const int o = o0 + nt * 16 + lo;                                  \
      const int kc = o >> 3, hh = o & 7;                                \
      _Pragma("unroll")                                                 \
      for (int rt = 0; rt < 2; ++rt) {                                  \
        _Pragma("unroll")                                               \
        for (int r = 0; r < 4; ++r) {                                   \
          const int t2l = (rt * 16 + quad * 4 + r) * 8 + hh;            \
          lds[t2l * 136 + kc] = (VALEXPR);                              \
        }                                                               \
      }                                                                 \
    }                                                                   \
    __syncthreads();                                                    \
    _Pragma("unroll")                                                   \
    for (int p = 0; p < 8; ++p) {                                       \
      const int idx = p * 512 + tid;                                    \
      const int a = idx >> 4, c8 = (idx & 15) * 8;                      \
      *(f16x8*)(DST + ((int64_t)m * 1024 + t2b + a) * 128 + c8) =       \
          *(const f16x8*)&lds[a * 136 + c8];                            \
    }                                                                   \
  }

__global__ __launch_bounds__(512) void k1_conv(
    const f16* __restrict__ xh, const f16* __restrict__ xl,
    const f16* __restrict__ Wqh, const f16* __restrict__ Wql,
    const f16* __restrict__ Wkh, const f16* __restrict__ Wkl,
    const f16* __restrict__ Wvb,
    const float* __restrict__ bq, const float* __restrict__ bk,
    const float* __restrict__ bv,
    f16* __restrict__ q3h, f16* __restrict__ q3l,
    f16* __restrict__ k3h, f16* __restrict__ k3l,
    f16* __restrict__ v3T) {
  __shared__ f16 lds[34816];  // max(256*136, 128*264) elems
  const int tid = threadIdx.x;
  const int w = tid >> 6, lane = tid & 63;
  const int quad = lane >> 4, lo = lane & 15;
  const int r0 = blockIdx.x * 32;     // rows r0..r0+31 (same b, same m)
  const int bb = r0 >> 10;
  const int m  = r0 >> 7;
  const int t2b = (r0 & 127) * 8;
  const int o0 = w * 128;             // each wave owns 128 channels

  // ---- V pass first (1 tap, hi only) so its accumulators die early ----
  {
    f32x4 av[2][8];
#pragma unroll
    for (int rt = 0; rt < 2; ++rt)
#pragma unroll
      for (int i = 0; i < 8; ++i)
#pragma unroll
        for (int r = 0; r < 4; ++r) av[rt][i][r] = 0.f;

#pragma unroll
    for (int kk = 0; kk < 4; ++kk) {
      const int koff = kk * 32 + quad * 8;
      f16x8 ah[2];
#pragma unroll
      for (int rt = 0; rt < 2; ++rt) {
        const int tt = (r0 + rt * 16 + lo) & 1023;
        ah[rt] = ldfrag(xh + ((int64_t)(bb * 1024 + tt)) * 128 + koff);
      }
#pragma unroll
      for (int nt = 0; nt < 8; ++nt) {
        const int n = o0 + nt * 16 + lo;
        f16x8 bv8 = ldfrag(Wvb + (int64_t)n * 128 + koff);
        av[0][nt] = MFMA16(ah[0], bv8, av[0][nt]);
        av[1][nt] = MFMA16(ah[1], bv8, av[1][nt]);
      }
    }
    // bias then stage v3T via LDS [kc][t2l] (stride 264), coalesced out
#pragma unroll
    for (int nt = 0; nt < 8; ++nt) {
      const int o = o0 + nt * 16 + lo;
      const float vbv = bv[o];
      const int kc = o >> 3, hh = o & 7;
#pragma unroll
      for (int rt = 0; rt < 2; ++rt)
#pragma unroll
        for (int r = 0; r < 4; ++r) {
          const int t2l = (rt * 16 + quad * 4 + r) * 8 + hh;
          lds[kc * 264 + t2l] = (f16)(av[rt][nt][r] + vbv);
        }
    }
    __syncthreads();
#pragma unroll
    for (int p = 0; p < 8; ++p) {
      const int idx = p * 512 + tid;
      const int kc = idx >> 5, t8 = (idx & 31) * 8;
      *(f16x8*)(v3T + ((int64_t)m * 128 + kc) * 1024 + t2b + t8) =
          *(const f16x8*)&lds[kc * 264 + t8];
    }
  }

  // ---- Q/K main loop: 5 taps, split-f16 (3 MFMAs per tap) ----
  f32x4 aq[2][8], ak[2][8];
#pragma unroll
  for (int rt = 0; rt < 2; ++rt)
#pragma unroll
    for (int i = 0; i < 8; ++i)
#pragma unroll
      for (int r = 0; r < 4; ++r) { aq[rt][i][r] = 0.f; ak[rt][i][r] = 0.f; }

#pragma unroll
  for (int j = 0; j < 5; ++j) {
    bool ok[2]; int64_t xoff[2];
#pragma unroll
    for (int rt = 0; rt < 2; ++rt) {
      const int tt = (r0 + rt * 16 + lo) & 1023;
      const int tp = tt + j - 4;            // causal left-pad 4
      ok[rt] = (tp >= 0);
      xoff[rt] = ((int64_t)(bb * 1024 + (ok[rt] ? tp : 0))) * 128;
    }
#pragma unroll
    for (int kk = 0; kk < 4; ++kk) {
      const int koff = kk * 32 + quad * 8;
      f16x8 ah[2], al[2];
#pragma unroll
      for (int rt = 0; rt < 2; ++rt) {
        ah[rt] = ldfrag(xh + xoff[rt] + koff);
        al[rt] = ldfrag(xl + xoff[rt] + koff);
        if (!ok[rt]) {
#pragma unroll
          for (int e = 0; e < 8; ++e) { ah[rt][e] = (f16)0; al[rt][e] = (f16)0; }
        }
      }
#pragma unroll
      for (int nt = 0; nt < 8; ++nt) {
        const int n = o0 + nt * 16 + lo;
        const int64_t wi = (int64_t)j * 131072 + (int64_t)n * 128 + koff;
        f16x8 bh = ldfrag(Wqh + wi);
        f16x8 bl = ldfrag(Wql + wi);
#pragma unroll
        for (int rt = 0; rt < 2; ++rt) {
          aq[rt][nt] = MFMA16(ah[rt], bh, aq[rt][nt]);
          aq[rt][nt] = MFMA16(ah[rt], bl, aq[rt][nt]);
          aq[rt][nt] = MFMA16(al[rt], bh, aq[rt][nt]);
        }
        bh = ldfrag(Wkh + wi);
        bl = ldfrag(Wkl + wi);
#pragma unroll
        for (int rt = 0; rt < 2; ++rt) {
          ak[rt][nt] = MFMA16(ah[rt], bh, ak[rt][nt]);
          ak[rt][nt] = MFMA16(ah[rt], bl, ak[rt][nt]);
          ak[rt][nt] = MFMA16(al[rt], bh, ak[rt][nt]);
        }
      }
    }
  }

  // bias + scale folded into accumulators
  const float SC = 0.29730177875068026f;  // 128^-0.25
#pragma unroll
  for (int nt = 0; nt < 8; ++nt) {
    const int o = o0 + nt * 16 + lo;
    const float vbq = bq[o], vbk = bk[o];
#pragma unroll
    for (int rt = 0; rt < 2; ++rt)
#pragma unroll
      for (int r = 0; r < 4; ++r) {
        aq[rt][nt][r] = (aq[rt][nt][r] + vbq) * SC;
        ak[rt][nt][r] = (ak[rt][nt][r] + vbk) * SC;
      }
  }

  STAGE_QK(q3h, (f16)aq[rt][nt][r])
  STAGE_QK(q3l, (f16)(aq[rt][nt][r] - (float)(f16)aq[rt][nt][r]))
  STAGE_QK(k3h, (f16)ak[rt][nt][r])
  STAGE_QK(k3l, (f16)(ak[rt][nt][r] - (float)(f16)ak[rt][nt][r]))
}

// ---------------- K2: scores S = Q3 @ K3^T (split-f16), fp32 out -----------
__global__ __launch_bounds__(256) void k2_scores(
    const f16* __restrict__ q3h, const f16* __restrict__ q3l,
    const f16* __restrict__ k3h, const f16* __restrict__ k3l,
    float* __restrict__ SP, int m_base) {
  const int w = threadIdx.x >> 6, lane = threadIdx.x & 63;
  const int quad = lane >> 4, lo = lane & 15;
  const int mm = blockIdx.z;
  const int m = m_base + mm;
  const int r0 = blockIdx.x * 64 + w * 16;  // t2 rows
  const int s0 = blockIdx.y * 128;          // s cols

  f32x4 acc[8];
#pragma unroll
  for (int i = 0; i < 8; ++i)
#pragma unroll
    for (int r = 0; r < 4; ++r) acc[i][r] = 0.f;

  const int64_t qoff = ((int64_t)m * 1024 + r0 + lo) * 128;
  const int64_t koffb = ((int64_t)m * 1024 + s0 + lo) * 128;
#pragma unroll
  for (int kk = 0; kk < 4; ++kk) {
    const int koff = kk * 32 + quad * 8;
    f16x8 ah = ldfrag(q3h + qoff + koff);
    f16x8 al = ldfrag(q3l + qoff + koff);
#pragma unroll
    for (int nt = 0; nt < 8; ++nt) {
      const int64_t bi = koffb + (int64_t)nt * 16 * 128 + koff;
      f16x8 bh = ldfrag(k3h + bi);
      f16x8 bl = ldfrag(k3l + bi);
      acc[nt] = MFMA16(ah, bh, acc[nt]);
      acc[nt] = MFMA16(ah, bl, acc[nt]);
      acc[nt] = MFMA16(al, bh, acc[nt]);
    }
  }
#pragma unroll
  for (int nt = 0; nt < 8; ++nt)
#pragma unroll
    for (int r = 0; r < 4; ++r) {
      const int row = r0 + quad * 4 + r, col = s0 + nt * 16 + lo;
      SP[((int64_t)mm * 1024 + row) * 1024 + col] = acc[nt][r];
    }
}

// ---------------- K3: exact fp32 top-64 + rowmin + causal + softmax --------
__global__ __launch_bounds__(256) void k3_select(
    const float* __restrict__ SP, f16* __restrict__ P) {
  const int w = threadIdx.x >> 6, lane = threadIdx.x & 63;
  const int t2 = blockIdx.x * 4 + w;  // one wave per row
  const int mm = blockIdx.y;
  const float* row = SP + ((int64_t)mm * 1024 + t2) * 1024;
  const float4* row4 = (const float4*)row;

  // element s(i,e) = i*256 + lane*4 + e
  float v[16];
  unsigned key[16];
  float mn = 1e30f;
  unsigned kmax = 0, kmin = 0xFFFFFFFFu;
#pragma unroll
  for (int i = 0; i < 4; ++i) {
    const float4 f4 = row4[i * 64 + lane];
    const float fe[4] = {f4.x, f4.y, f4.z, f4.w};
#pragma unroll
    for (int e = 0; e < 4; ++e) {
      const float f = fe[e];
      v[i * 4 + e] = f;
      const unsigned u = __builtin_bit_cast(unsigned, f);
      const unsigned k = (u & 0x80000000u) ? ~u : (u | 0x80000000u);  // monotonic
      key[i * 4 + e] = k;
      mn = fminf(mn, f);
      kmax = max(kmax, k);
      kmin = min(kmin, k);
    }
  }
  for (int off = 32; off; off >>= 1) {
    mn = fminf(mn, __shfl_xor(mn, off));
    kmax = max(kmax, (unsigned)__shfl_xor((int)kmax, off));
    kmin = min(kmin, (unsigned)__shfl_xor((int)kmin, off));
  }

  // largest T in [kmin, kmax] with count(key >= T) >= 64  (exact fp32 top-64)
  unsigned long long blo = kmin, bhi = kmax;
  while (blo < bhi) {
    const unsigned long long mid = blo + ((bhi - blo + 1) >> 1);
    int cnt = 0;
#pragma unroll
    for (int i = 0; i < 16; ++i) cnt += (key[i] >= (unsigned)mid) ? 1 : 0;
    for (int off = 32; off; off >>= 1) cnt += __shfl_xor(cnt, off);
    if (cnt >= 64) blo = mid; else bhi = mid - 1;
  }
  const unsigned kth = (unsigned)blo;

  float wv[16];
  float mx = -1e30f;
#pragma unroll
  for (int i = 0; i < 4; ++i)
#pragma unroll
    for (int e = 0; e < 4; ++e) {
      const int s = i * 256 + lane * 4 + e;
      const float ww = (key[i * 4 + e] >= kth) ? v[i * 4 + e] : mn;
      wv[i * 4 + e] = ww;
      if (s <= t2) mx = fmaxf(mx, ww);
    }
  for (int off = 32; off; off >>= 1) mx = fmaxf(mx, __shfl_xor(mx, off));

  float ev[16];
  float sum = 0.f;
#pragma unroll
  for (int i = 0; i < 4; ++i)
#pragma unroll
    for (int e = 0; e < 4; ++e) {
      const int s = i * 256 + lane * 4 + e;
      const float x = (s <= t2) ? expf(wv[i * 4 + e] - mx) : 0.f;
      ev[i * 4 + e] = x;
      sum += x;
    }
  for (int off = 32; off; off >>= 1) sum += __shfl_xor(sum, off);
  const float inv = 1.0f / sum;

  f16* prow = P + ((int64_t)mm * 1024 + t2) * 1024;
#pragma unroll
  for (int i = 0; i < 4; ++i) {
    f16x4 pk;
#pragma unroll
    for (int e = 0; e < 4; ++e) pk[e] = (f16)(ev[i * 4 + e] * inv);
    ((f16x4*)prow)[i * 64 + lane] = pk;
  }
}

// ---------------- K4: A = P @ V (per m) ------------------------------------
__global__ __launch_bounds__(256) void k4_pv(
    const f16* __restrict__ P, const f16* __restrict__ v3T,
    f16* __restrict__ A, int m_base) {
  const int w = threadIdx.x >> 6, lane = threadIdx.x & 63;
  const int quad = lane >> 4, lo = lane & 15;
  const int mm = blockIdx.y;
  const int m = m_base + mm;
  const int r0 = blockIdx.x * 64 + w * 16;

  f32x4 acc[8];
#pragma unroll
  for (int i = 0; i < 8; ++i)
#pragma unroll
    for (int r = 0; r < 4; ++r) acc[i][r] = 0.f;

  const f16* prow = P + ((int64_t)mm * 1024 + r0 + lo) * 1024;
  const f16* vbase = v3T + ((int64_t)m * 128 + lo) * 1024;
  for (int ks = 0; ks < 32; ++ks) {
    const int koff = ks * 32 + quad * 8;
    f16x8 a = ldfrag(prow + koff);
#pragma unroll
    for (int nt = 0; nt < 8; ++nt) {
      f16x8 fb = ldfrag(vbase + (int64_t)nt * 16 * 1024 + koff);
      acc[nt] = MFMA16(a, fb, acc[nt]);
    }
  }
#pragma unroll
  for (int nt = 0; nt < 8; ++nt)
#pragma unroll
    for (int r = 0; r < 4; ++r) {
      const int row = r0 + quad * 4 + r, col = nt * 16 + lo;
      A[((int64_t)m * 1024 + row) * 128 + col] = (f16)acc[nt][r];
    }
}

// ---------------- K5: gather + output projection + bias --------------------
__global__ __launch_bounds__(256) void k5_proj(
    const f16* __restrict__ A, const f16* __restrict__ Wub,
    const float* __restrict__ bu, float* __restrict__ out) {
  const int w = threadIdx.x >> 6, lane = threadIdx.x & 63;
  const int quad = lane >> 4, lo = lane & 15;
  const int r0 = blockIdx.x * 64 + w * 16;  // row in [0, 8192) = b*1024 + t2
  const int r = r0 + lo;
  const int bI = r >> 10, t2 = r & 1023;

  f32x4 acc[8];
#pragma unroll
  for (int i = 0; i < 8; ++i)
#pragma unroll
    for (int rr = 0; rr < 4; ++rr) acc[i][rr] = 0.f;

  for (int kk = 0; kk < 32; ++kk) {
    const int o = kk * 32 + quad * 8;  // feature index 0..1023
    const int j = o >> 7, kc = o & 127;
    f16x8 a = ldfrag(A + (((int64_t)(bI * 8 + j) * 1024 + t2) * 128 + kc));
#pragma unroll
    for (int nt = 0; nt < 8; ++nt) {
      f16x8 fb = ldfrag(Wub + (int64_t)(nt * 16 + lo) * 1024 + o);
      acc[nt] = MFMA16(a, fb, acc[nt]);
    }
  }
#pragma unroll
  for (int nt = 0; nt < 8; ++nt) {
    const int col = nt * 16 + lo;
    const float bias = bu[col];
#pragma unroll
    for (int rr = 0; rr < 4; ++rr) {
      const int row = r0 + quad * 4 + rr;
      out[(int64_t)row * 128 + col] = acc[nt][rr] + bias;
    }
  }
}

// ---------------- launcher --------------------------------------------------
extern "C" void kernel_launch(void* const* d_in, const int* in_sizes, int n_in,
                              void* d_out, int out_size, void* d_ws, size_t ws_size,
                              hipStream_t stream) {
  const float* x  = (const float*)d_in[0];
  const float* Wq = (const float*)d_in[1];
  const float* bq = (const float*)d_in[2];
  const float* Wk = (const float*)d_in[3];
  const float* bk = (const float*)d_in[4];
  const float* Wv = (const float*)d_in[5];
  const float* bv = (const float*)d_in[6];
  const float* Wu = (const float*)d_in[7];
  const float* bu = (const float*)d_in[8];
  float* out = (float*)d_out;

  char* ws = (char*)d_ws;
  f16* xh  = (f16*)ws;  ws += 2097152;
  f16* xl  = (f16*)ws;  ws += 2097152;
  f16* Wqh = (f16*)ws;  ws += 1310720;
  f16* Wql = (f16*)ws;  ws += 1310720;
  f16* Wkh = (f16*)ws;  ws += 1310720;
  f16* Wkl = (f16*)ws;  ws += 1310720;
  f16* Wvb = (f16*)ws;  ws += 262144;
  f16* Wub = (f16*)ws;  ws += 262144;
  f16* q3h = (f16*)ws;  ws += 16777216;           // 64*1024*128 fp16
  f16* q3l = (f16*)ws;  ws += 16777216;
  f16* k3h = (f16*)ws;  ws += 16777216;
  f16* k3l = (f16*)ws;  ws += 16777216;
  f16* v3T = (f16*)ws;  ws += 16777216;
  f16* A   = (f16*)ws;  ws += 16777216;
  // fixed bytes so far: 110,624,768
  // per-chunk: SP fp32 (mch*4 MiB) + P fp16 (mch*2 MiB)
  int mch = 16;
  while (mch > 1 &&
         (size_t)110624768 + (size_t)mch * 6291456 > ws_size) mch >>= 1;
  float* SP = (float*)ws;  ws += (size_t)mch * 4194304;
  f16*   P  = (f16*)ws;

  // K0: repack (exactly 2621440 threads = 10240 * 256)
  k0_prep<<<10240, 256, 0, stream>>>(x, Wq, Wk, Wv, Wu,
                                     xh, xl, Wqh, Wql, Wkh, Wkl, Wvb, Wub);

  // K1: convs + scramble; 1 block = 32 rows x 1024 ch, coalesced LDS-staged out
  k1_conv<<<256, 512, 0, stream>>>(xh, xl, Wqh, Wql, Wkh, Wkl, Wvb,
                                   bq, bk, bv, q3h, q3l, k3h, k3l, v3T);

  // attention in chunks of mch m-batches
  for (int m_base = 0; m_base < 64; m_base += mch) {
    k2_scores<<<dim3(16, 8, mch), 256, 0, stream>>>(q3h, q3l, k3h, k3l, SP, m_base);
    k3_select<<<dim3(256, mch), 256, 0, stream>>>(SP, P);
    k4_pv<<<dim3(16, mch), 256, 0, stream>>>(P, v3T, A, m_base);
  }

  // K5: projection (8192 rows / 64 per block)
  k5_proj<<<128, 256, 0, stream>>>(A, Wub, bu, out);

  (void)in_sizes; (void)n_in; (void)out_size; (void)ws_size;
}